// Round 1
// baseline (1268.683 us; speedup 1.0000x reference)
//
#include <hip/hip_runtime.h>

#define NND 50000
#define NE  800000
#define IND 128
#define HD  256
#define OD  256
#define NH  8
#define ED  64
#define KVIN 320   // 64 + 128 + 128

typedef __attribute__((ext_vector_type(8))) short bf16x8;
typedef __attribute__((ext_vector_type(4))) float f32x4;

__device__ __forceinline__ float bf2f(unsigned short u) {
    union { unsigned int i; float f; } x; x.i = ((unsigned int)u) << 16; return x.f;
}
__device__ __forceinline__ unsigned short f2bf(float f) {
    union { float f; unsigned int i; } x; x.f = f;
    unsigned int u = x.i;
    u += 0x7FFFu + ((u >> 16) & 1u);   // RNE
    return (unsigned short)(u >> 16);
}

// ---------------- weight pack ----------------
// P[((ct*KS+ks)*64 + l)*8 + j] = bf16( W[k*N + n] ),  n = ct*16 + (l&15),
// k = ks*32 + (l>>4)*8 + j.  B-fragment for mfma_f32_16x16x32_bf16 is then a
// fully-coalesced contiguous 16B load per lane.
__global__ void k_packw(const float* __restrict__ W, unsigned short* __restrict__ P,
                        int K, int N) {
    int tid = blockIdx.x * 256 + threadIdx.x;
    if (tid >= K * N) return;
    int j = tid & 7;
    int l = (tid >> 3) & 63;
    int rest = tid >> 9;
    int KS = K >> 5;
    int ks = rest % KS;
    int ct = rest / KS;
    int n = ct * 16 + (l & 15);
    int k = ks * 32 + (l >> 4) * 8 + j;
    P[tid] = f2bf(W[k * N + n]);
}

__global__ void k_h2bf(const float* __restrict__ h, unsigned short* __restrict__ hb, int n4) {
    int i = blockIdx.x * 256 + threadIdx.x;
    if (i < n4) {
        float4 v = *(const float4*)(h + (size_t)i * 4);
        ushort4 o;
        o.x = f2bf(v.x); o.y = f2bf(v.y); o.z = f2bf(v.z); o.w = f2bf(v.w);
        *(ushort4*)(hb + (size_t)i * 4) = o;
    }
}

// ---------------- MFMA helpers ----------------
__device__ __forceinline__ void zero_acc(f32x4 (&acc)[4][4]) {
    #pragma unroll
    for (int i = 0; i < 4; ++i)
        #pragma unroll
        for (int c = 0; c < 4; ++c)
            #pragma unroll
            for (int r = 0; r < 4; ++r) acc[i][c][r] = 0.f;
}

// A: LDS tile [64][STRIDE] bf16 (rows = M).  Wp: packed weights.
// Wave w computes cols 64w..64w+63 for all 64 rows: acc[i][c] is the
// (rows 16i..16i+15) x (cols 64w+16c..+15) fragment.
template<int KS, int STRIDE>
__device__ __forceinline__ void gemm_step(const unsigned short* A,
                                          const unsigned short* __restrict__ Wp,
                                          int w, int l, f32x4 (&acc)[4][4]) {
    for (int ks = 0; ks < KS; ++ks) {
        bf16x8 a[4], b[4];
        #pragma unroll
        for (int i = 0; i < 4; ++i)
            a[i] = *(const bf16x8*)(A + (i * 16 + (l & 15)) * STRIDE + ks * 32 + (l >> 4) * 8);
        #pragma unroll
        for (int c = 0; c < 4; ++c)
            b[c] = *(const bf16x8*)(Wp + (((4 * w + c) * KS + ks) * 64 + l) * 8);
        #pragma unroll
        for (int i = 0; i < 4; ++i)
            #pragma unroll
            for (int c = 0; c < 4; ++c)
                acc[i][c] = __builtin_amdgcn_mfma_f32_16x16x32_bf16(a[i], b[c], acc[i][c], 0, 0, 0);
    }
}

// ---------------- Q = MLP(h) ----------------
__global__ __launch_bounds__(256) void k_qmlp(
    const unsigned short* __restrict__ hb,
    const unsigned short* __restrict__ W1p, const float* __restrict__ b1,
    const unsigned short* __restrict__ W2p, const float* __restrict__ b2,
    unsigned short* __restrict__ qb)
{
    __shared__ unsigned short sX[64][136];   // 128 + 8 pad
    __shared__ unsigned short sH[64][264];   // 256 + 8 pad
    const int t = threadIdx.x, w = t >> 6, l = t & 63;
    const int m0 = blockIdx.x * 64;

    for (int c = t; c < 1024; c += 256) {
        int row = c >> 4, j = c & 15;
        int srcr = m0 + row; if (srcr >= NND) srcr = NND - 1;
        *(bf16x8*)(&sX[row][j * 8]) = *(const bf16x8*)(hb + (size_t)srcr * IND + j * 8);
    }
    __syncthreads();

    f32x4 acc[4][4];
    zero_acc(acc);
    gemm_step<4, 136>(&sX[0][0], W1p, w, l, acc);

    float bias1[4];
    #pragma unroll
    for (int c = 0; c < 4; ++c) bias1[c] = b1[64 * w + 16 * c + (l & 15)];
    #pragma unroll
    for (int i = 0; i < 4; ++i)
        #pragma unroll
        for (int c = 0; c < 4; ++c)
            #pragma unroll
            for (int r = 0; r < 4; ++r) {
                float v = acc[i][c][r] + bias1[c];
                v = v > 0.f ? v : 0.f;
                sH[i * 16 + (l >> 4) * 4 + r][64 * w + 16 * c + (l & 15)] = f2bf(v);
            }
    __syncthreads();

    zero_acc(acc);
    gemm_step<8, 264>(&sH[0][0], W2p, w, l, acc);

    float bias2[4];
    #pragma unroll
    for (int c = 0; c < 4; ++c) bias2[c] = b2[64 * w + 16 * c + (l & 15)];
    #pragma unroll
    for (int i = 0; i < 4; ++i)
        #pragma unroll
        for (int c = 0; c < 4; ++c)
            #pragma unroll
            for (int r = 0; r < 4; ++r) {
                int row = m0 + i * 16 + (l >> 4) * 4 + r;
                if (row < NND)
                    qb[(size_t)row * OD + 64 * w + 16 * c + (l & 15)] =
                        f2bf(acc[i][c][r] + bias2[c]);
            }
}

// ---------------- per-edge MLP passes ----------------
// MODE 0: k = MLP_k(kv); logits = q[dst].k / sqrt(32); ex = exp; den += ex
// MODE 1: v = MLP_v(kv); out[dst] += (ex/den[dst]) * v
template<int MODE>
__global__ __launch_bounds__(256) void k_edge(
    const float* __restrict__ eattr,
    const unsigned short* __restrict__ hb,
    const int* __restrict__ eidx,
    const unsigned short* __restrict__ W1p, const float* __restrict__ b1,
    const unsigned short* __restrict__ W2p, const float* __restrict__ b2,
    const unsigned short* __restrict__ qb,
    float* __restrict__ exbuf,
    float* __restrict__ den,
    float* __restrict__ outp)
{
    __shared__ unsigned short sX[64][328];   // 320 + 8 pad
    __shared__ unsigned short sH[64][264];   // 256 + 8 pad
    __shared__ int sSrc[64], sDst[64];
    __shared__ float sAlpha[512];
    const int t = threadIdx.x, w = t >> 6, l = t & 63;
    const int e0 = blockIdx.x * 64;

    if (t < 64) { sSrc[t] = eidx[e0 + t]; sDst[t] = eidx[NE + e0 + t]; }
    // stage edge attrs (cols 0..63), fp32 -> bf16
    for (int c = t; c < 1024; c += 256) {
        int row = c >> 4, j = c & 15;
        float4 v = *(const float4*)(eattr + (size_t)(e0 + row) * ED + j * 4);
        ushort4 o; o.x = f2bf(v.x); o.y = f2bf(v.y); o.z = f2bf(v.z); o.w = f2bf(v.w);
        *(ushort4*)(&sX[row][j * 4]) = o;
    }
    __syncthreads();
    // gather h[dst] (cols 64..191) and h[src] (cols 192..319)
    for (int c = t; c < 1024; c += 256) {
        int row = c >> 4, j = c & 15;
        *(bf16x8*)(&sX[row][64 + j * 8]) = *(const bf16x8*)(hb + (size_t)sDst[row] * IND + j * 8);
    }
    for (int c = t; c < 1024; c += 256) {
        int row = c >> 4, j = c & 15;
        *(bf16x8*)(&sX[row][192 + j * 8]) = *(const bf16x8*)(hb + (size_t)sSrc[row] * IND + j * 8);
    }
    if (MODE == 1) {
        for (int p = t; p < 512; p += 256) {
            int er = p >> 3, hh = p & 7;
            sAlpha[p] = exbuf[(size_t)(e0 + er) * NH + hh] / den[sDst[er] * NH + hh];
        }
    }
    __syncthreads();

    f32x4 acc[4][4];
    zero_acc(acc);
    gemm_step<10, 328>(&sX[0][0], W1p, w, l, acc);

    float bias1[4];
    #pragma unroll
    for (int c = 0; c < 4; ++c) bias1[c] = b1[64 * w + 16 * c + (l & 15)];
    #pragma unroll
    for (int i = 0; i < 4; ++i)
        #pragma unroll
        for (int c = 0; c < 4; ++c)
            #pragma unroll
            for (int r = 0; r < 4; ++r) {
                float v = acc[i][c][r] + bias1[c];
                v = v > 0.f ? v : 0.f;
                sH[i * 16 + (l >> 4) * 4 + r][64 * w + 16 * c + (l & 15)] = f2bf(v);
            }
    __syncthreads();

    zero_acc(acc);
    gemm_step<8, 264>(&sH[0][0], W2p, w, l, acc);

    float bias2[4];
    #pragma unroll
    for (int c = 0; c < 4; ++c) bias2[c] = b2[64 * w + 16 * c + (l & 15)];

    if (MODE == 0) {
        __syncthreads();   // all waves done reading sH
        #pragma unroll
        for (int i = 0; i < 4; ++i)
            #pragma unroll
            for (int c = 0; c < 4; ++c)
                #pragma unroll
                for (int r = 0; r < 4; ++r)
                    sH[i * 16 + (l >> 4) * 4 + r][64 * w + 16 * c + (l & 15)] =
                        f2bf(acc[i][c][r] + bias2[c]);
        __syncthreads();
        const float scale = 0.17677669529663687f;   // 1/sqrt(32)
        for (int p = t; p < 512; p += 256) {
            int er = p >> 3, hh = p & 7;
            int dn = sDst[er];
            const unsigned short* qrow = qb + (size_t)dn * OD + hh * 32;
            float s = 0.f;
            #pragma unroll
            for (int jj = 0; jj < 32; jj += 8) {
                bf16x8 qv = *(const bf16x8*)(qrow + jj);
                bf16x8 kv = *(const bf16x8*)(&sH[er][hh * 32 + jj]);
                #pragma unroll
                for (int u = 0; u < 8; ++u)
                    s += bf2f((unsigned short)qv[u]) * bf2f((unsigned short)kv[u]);
            }
            float ex = __expf(s * scale);
            exbuf[(size_t)(e0 + er) * NH + hh] = ex;
            atomicAdd(&den[dn * NH + hh], ex);
        }
    } else {
        #pragma unroll
        for (int i = 0; i < 4; ++i)
            #pragma unroll
            for (int c = 0; c < 4; ++c) {
                int col = 64 * w + 16 * c + (l & 15);
                int hh = col >> 5;
                #pragma unroll
                for (int r = 0; r < 4; ++r) {
                    int er = i * 16 + (l >> 4) * 4 + r;
                    float v = (acc[i][c][r] + bias2[c]) * sAlpha[er * NH + hh];
                    atomicAdd(outp + (size_t)sDst[er] * OD + col, v);
                }
            }
    }
}

// ---------------- launcher ----------------
extern "C" void kernel_launch(void* const* d_in, const int* in_sizes, int n_in,
                              void* d_out, int out_size, void* d_ws, size_t ws_size,
                              hipStream_t stream)
{
    const float* h   = (const float*)d_in[0];
    const float* e   = (const float*)d_in[1];
    const int*   eid = (const int*)  d_in[2];
    const float* Wk1 = (const float*)d_in[3];
    const float* bk1 = (const float*)d_in[4];
    const float* Wk2 = (const float*)d_in[5];
    const float* bk2 = (const float*)d_in[6];
    const float* Wv1 = (const float*)d_in[7];
    const float* bv1 = (const float*)d_in[8];
    const float* Wv2 = (const float*)d_in[9];
    const float* bv2 = (const float*)d_in[10];
    const float* Wq1 = (const float*)d_in[11];
    const float* bq1 = (const float*)d_in[12];
    const float* Wq2 = (const float*)d_in[13];
    const float* bq2 = (const float*)d_in[14];

    // workspace layout (bytes)
    char* ws = (char*)d_ws;
    unsigned short* hb   = (unsigned short*)(ws + 0);            // 12,800,000
    unsigned short* Wq1p = (unsigned short*)(ws + 12800000);     //     65,536
    unsigned short* Wq2p = (unsigned short*)(ws + 12865536);     //    131,072
    unsigned short* Wk1p = (unsigned short*)(ws + 12996608);     //    163,840
    unsigned short* Wk2p = (unsigned short*)(ws + 13160448);     //    131,072
    unsigned short* Wv1p = (unsigned short*)(ws + 13291520);     //    163,840
    unsigned short* Wv2p = (unsigned short*)(ws + 13455360);     //    131,072
    unsigned short* qb   = (unsigned short*)(ws + 13586432);     // 25,600,000
    float*          exb  = (float*)         (ws + 39186432);     // 25,600,000
    float*          den  = (float*)         (ws + 64786432);     //  1,600,000
    const size_t needed = 66386432;
    if (ws_size < needed) return;   // insufficient scratch -> fail validation visibly

    hipMemsetAsync(d_out, 0, (size_t)NND * OD * sizeof(float), stream);
    hipMemsetAsync(den, 0, (size_t)NND * NH * sizeof(float), stream);

    k_h2bf<<<(NND * IND / 4 + 255) / 256, 256, 0, stream>>>(h, hb, NND * IND / 4);
    k_packw<<<(IND * HD + 255) / 256, 256, 0, stream>>>(Wq1, Wq1p, IND, HD);
    k_packw<<<(HD * OD + 255) / 256, 256, 0, stream>>>(Wq2, Wq2p, HD, OD);
    k_packw<<<(KVIN * HD + 255) / 256, 256, 0, stream>>>(Wk1, Wk1p, KVIN, HD);
    k_packw<<<(HD * OD + 255) / 256, 256, 0, stream>>>(Wk2, Wk2p, HD, OD);
    k_packw<<<(KVIN * HD + 255) / 256, 256, 0, stream>>>(Wv1, Wv1p, KVIN, HD);
    k_packw<<<(HD * OD + 255) / 256, 256, 0, stream>>>(Wv2, Wv2p, HD, OD);

    k_qmlp<<<(NND + 63) / 64, 256, 0, stream>>>(hb, Wq1p, bq1, Wq2p, bq2, qb);

    k_edge<0><<<NE / 64, 256, 0, stream>>>(e, hb, eid, Wk1p, bk1, Wk2p, bk2,
                                           qb, exb, den, nullptr);
    k_edge<1><<<NE / 64, 256, 0, stream>>>(e, hb, eid, Wv1p, bv1, Wv2p, bv2,
                                           nullptr, exb, den, (float*)d_out);
}